// Round 1
// baseline (510.904 us; speedup 1.0000x reference)
//
#include <hip/hip_runtime.h>
#include <math.h>

#define BATCH 32
#define NH 32
#define NKVH 8
#define GRP 4
#define HD 128
#define BLKSZ 16
#define MAXB 128
#define PART 256
#define NPART 8
#define SCALE 0.08838834764831845f
#define NEGINF (-1e30f)

// ws layout (float elements):
#define WS_QROT 0                            // B*H*D      = 131072
#define WS_KROT (BATCH*NH*HD)                // +B*KVH*D   =  32768
#define WS_ML   (WS_KROT + BATCH*NKVH*HD)    // +B*KVH*G*NPART*2 = 16384
#define WS_OP   (WS_ML + BATCH*NKVH*GRP*NPART*2) // +B*KVH*G*NPART*D = 1048576
// total = 1,228,800 floats = 4.69 MB of d_ws

__global__ void rope_prep(const float* __restrict__ q,
                          const float* __restrict__ nk,
                          const int* __restrict__ ctx,
                          float* __restrict__ ws) {
    int b = blockIdx.x;
    int t = threadIdx.x;          // 0..127
    __shared__ float cs[64], sn[64];
    if (t < 64) {
        double f = pow(10000.0, -(double)t / 64.0);
        double a = (double)ctx[b] * f;      // pos = context_lens (per reference)
        cs[t] = (float)cos(a);
        sn[t] = (float)sin(a);
    }
    __syncthreads();
    int d = t;
    float c = cs[d & 63], s = sn[d & 63];
    for (int h = 0; h < NH; ++h) {
        const float* qp = q + ((size_t)b * NH + h) * HD;
        float x = qp[d];
        float y = qp[d ^ 64];
        float r = (d < 64) ? (x * c - y * s) : (x * c + y * s);
        ws[WS_QROT + ((size_t)b * NH + h) * HD + d] = r;
    }
    for (int kh = 0; kh < NKVH; ++kh) {
        const float* kp = nk + ((size_t)b * NKVH + kh) * HD;
        float x = kp[d];
        float y = kp[d ^ 64];
        float r = (d < 64) ? (x * c - y * s) : (x * c + y * s);
        ws[WS_KROT + ((size_t)b * NKVH + kh) * HD + d] = r;
    }
}

__global__ __launch_bounds__(256)
void attn_partial(const float* __restrict__ kc,
                  const float* __restrict__ vc,
                  const float* __restrict__ nv,
                  const int* __restrict__ btab,
                  const int* __restrict__ ctx,
                  float* __restrict__ ws) {
    int part = blockIdx.x, kvh = blockIdx.y, b = blockIdx.z;
    int L = ctx[b];
    int start = part * PART;
    if (start >= L) return;                  // invalid partition: reducer skips it
    int end = min(start + PART, L);
    int n = end - start;
    int tok = L - 1;                         // new-token slot (read from roped nk / nv)

    int tid = threadIdx.x;
    int hw = tid >> 5;                       // half-wave 0..7, one token at a time
    int hl = tid & 31;                       // lane-in-half-wave, covers d = 4*hl..4*hl+3
    int wave = tid >> 6;                     // 0..3, one softmax head per wave
    int lane = tid & 63;

    __shared__ float sc[GRP][PART];          // 4 KB scores -> exp'd probs
    __shared__ float oacc[8][GRP][HD];       // 16 KB half-wave partial outputs

    // q fragments for this lane: 4 heads x float4 (roped, from ws)
    const float* qrot = ws + WS_QROT + ((size_t)b * NH + kvh * GRP) * HD;
    float4 qa[GRP];
#pragma unroll
    for (int g = 0; g < GRP; ++g)
        qa[g] = *(const float4*)(qrot + g * HD + 4 * hl);

    const float* krot = ws + WS_KROT + ((size_t)b * NKVH + kvh) * HD;
    const int* bt = btab + b * MAXB;

    // ---- Phase 1: scores = (q . k) * scale ----
    for (int s = start + hw; s < end; s += 8) {
        float4 k4;
        if (s == tok) {
            k4 = *(const float4*)(krot + 4 * hl);
        } else {
            int blk = bt[s >> 4];
            const float* kp = kc + (((size_t)blk * BLKSZ + (s & 15)) * NKVH + kvh) * HD;
            k4 = *(const float4*)(kp + 4 * hl);
        }
        float p[GRP];
#pragma unroll
        for (int g = 0; g < GRP; ++g)
            p[g] = qa[g].x * k4.x + qa[g].y * k4.y + qa[g].z * k4.z + qa[g].w * k4.w;
#pragma unroll
        for (int off = 16; off >= 1; off >>= 1) {
#pragma unroll
            for (int g = 0; g < GRP; ++g)
                p[g] += __shfl_xor(p[g], off, 32);
        }
        if (hl == 0) {
#pragma unroll
            for (int g = 0; g < GRP; ++g)
                sc[g][s - start] = p[g] * SCALE;
        }
    }
    __syncthreads();

    // ---- Phase 2: softmax (unnormalized), wave w owns head w ----
    {
        int g = wave;
        float m = NEGINF;
        for (int i = lane; i < n; i += 64) m = fmaxf(m, sc[g][i]);
#pragma unroll
        for (int off = 32; off >= 1; off >>= 1) m = fmaxf(m, __shfl_xor(m, off));
        float sum = 0.f;
        for (int i = lane; i < n; i += 64) {
            float e = __expf(sc[g][i] - m);
            sc[g][i] = e;
            sum += e;
        }
#pragma unroll
        for (int off = 32; off >= 1; off >>= 1) sum += __shfl_xor(sum, off);
        if (lane == 0) {
            size_t mlidx = ((((size_t)b * NKVH + kvh) * GRP + g) * NPART + part) * 2;
            ws[WS_ML + mlidx] = m;
            ws[WS_ML + mlidx + 1] = sum;
        }
    }
    __syncthreads();

    // ---- Phase 3: o = sum_s p[s] * V[s] ----
    float4 acc[GRP];
#pragma unroll
    for (int g = 0; g < GRP; ++g) acc[g] = make_float4(0.f, 0.f, 0.f, 0.f);

    for (int s = start + hw; s < end; s += 8) {
        float4 v4;
        if (s == tok) {
            v4 = *(const float4*)(nv + ((size_t)b * NKVH + kvh) * HD + 4 * hl);
        } else {
            int blk = bt[s >> 4];
            const float* vp = vc + (((size_t)blk * BLKSZ + (s & 15)) * NKVH + kvh) * HD;
            v4 = *(const float4*)(vp + 4 * hl);
        }
        int i = s - start;
#pragma unroll
        for (int g = 0; g < GRP; ++g) {
            float e = sc[g][i];                 // same addr across half-wave: LDS broadcast
            acc[g].x += e * v4.x; acc[g].y += e * v4.y;
            acc[g].z += e * v4.z; acc[g].w += e * v4.w;
        }
    }
#pragma unroll
    for (int g = 0; g < GRP; ++g)
        *(float4*)&oacc[hw][g][4 * hl] = acc[g];
    __syncthreads();

    for (int o = tid; o < GRP * HD; o += 256) {
        int g = o >> 7, d = o & 127;
        float ssum = 0.f;
#pragma unroll
        for (int w = 0; w < 8; ++w) ssum += oacc[w][g][d];
        ws[WS_OP + ((((size_t)b * NKVH + kvh) * GRP + g) * NPART + part) * HD + d] = ssum;
    }
}

__global__ __launch_bounds__(128)
void attn_reduce(const int* __restrict__ ctx,
                 const float* __restrict__ ws,
                 float* __restrict__ out) {
    int bh = blockIdx.x;
    int b = bh >> 5;
    int h = bh & 31;
    int kvh = h >> 2, g = h & 3;
    int L = ctx[b];
    int np = min(NPART, (L + PART - 1) / PART);
    size_t base = (((size_t)b * NKVH + kvh) * GRP + g) * NPART;
    float M = NEGINF;
    for (int p = 0; p < np; ++p)
        M = fmaxf(M, ws[WS_ML + (base + p) * 2]);
    float w_[NPART];
    float Lsum = 0.f;
    for (int p = 0; p < np; ++p) {
        float e = __expf(ws[WS_ML + (base + p) * 2] - M);
        w_[p] = e;
        Lsum += e * ws[WS_ML + (base + p) * 2 + 1];
    }
    float inv = 1.0f / Lsum;
    int d = threadIdx.x;
    float acc = 0.f;
    for (int p = 0; p < np; ++p)
        acc += w_[p] * ws[WS_OP + (base + p) * HD + d];
    out[((size_t)b * NH + h) * HD + d] = acc * inv;
}

extern "C" void kernel_launch(void* const* d_in, const int* in_sizes, int n_in,
                              void* d_out, int out_size, void* d_ws, size_t ws_size,
                              hipStream_t stream) {
    const float* q    = (const float*)d_in[0];
    const float* nk   = (const float*)d_in[1];
    const float* nv   = (const float*)d_in[2];
    const float* kc   = (const float*)d_in[3];
    const float* vc   = (const float*)d_in[4];
    const int*   btab = (const int*)d_in[5];
    const int*   ctx  = (const int*)d_in[6];
    float* out = (float*)d_out;
    float* ws  = (float*)d_ws;

    rope_prep<<<dim3(BATCH), dim3(128), 0, stream>>>(q, nk, ctx, ws);
    attn_partial<<<dim3(NPART, NKVH, BATCH), dim3(256), 0, stream>>>(kc, vc, nv, btab, ctx, ws);
    attn_reduce<<<dim3(BATCH * NH), dim3(128), 0, stream>>>(ctx, ws, out);
}